// Round 16
// baseline (9854.860 us; speedup 1.0000x reference)
//
#include <hip/hip_runtime.h>
#include <math.h>

namespace {
constexpr int   Bb    = 16;
constexpr int   Nn    = 2048;
constexpr int   Mm    = 2048;
constexpr float EPSf  = 0.005f;
constexpr float TOLf  = 1e-3f;
constexpr int   MAXIT = 100;
constexpr float LN2f  = 0.69314718055994531f;
constexpr float L2Ef  = 1.44269504088896340f;  // log2(e)
constexpr float C2f   = 288.53900817779268f;   // log2(e)/EPS
constexpr int   BLOCK = 256;
constexpr int   PGRID = 1024;                  // 64 blocks/batch, 32 rows/block
constexpr int   BPB   = 64;                    // blocks per batch
constexpr int   NCH   = 64;                    // 32-pt chunks per batch
}

#define AGT __HIP_MEMORY_SCOPE_AGENT
__device__ __forceinline__ float ex2(float x) { return __builtin_amdgcn_exp2f(x); }
__device__ __forceinline__ float aload(const float* p) {
  return __hip_atomic_load(p, __ATOMIC_RELAXED, AGT);
}
__device__ __forceinline__ void astore(float* p, float v) {
  __hip_atomic_store(p, v, __ATOMIC_RELAXED, AGT);
}

__global__ __launch_bounds__(BLOCK) void pack_pts(const float* __restrict__ p,
                                                  float4* __restrict__ pk, int npts) {
  int i = blockIdx.x * BLOCK + threadIdx.x;
  if (i < npts) pk[i] = make_float4(p[3 * i], p[3 * i + 1], p[3 * i + 2], 0.0f);
}

__global__ __launch_bounds__(BLOCK) void init_bar(unsigned* bar) {
  for (int i = threadIdx.x; i < 544; i += BLOCK) bar[i] = 0u;
}

__global__ __launch_bounds__(BLOCK) void bbox_k(const float4* __restrict__ pk1,
                                                const float4* __restrict__ pk2,
                                                float4* __restrict__ bbox) {
  __shared__ float4 smin[BLOCK], smax[BLOCK];
  const int cb = blockIdx.x;
  const float4* p = (cb < 16 ? pk1 : pk2) + (cb & 15) * Nn;
  float4 mn = make_float4(3e38f, 3e38f, 3e38f, 0), mx = make_float4(-3e38f, -3e38f, -3e38f, 0);
  for (int i = threadIdx.x; i < Nn; i += BLOCK) {
    float4 v = p[i];
    mn.x = fminf(mn.x, v.x); mn.y = fminf(mn.y, v.y); mn.z = fminf(mn.z, v.z);
    mx.x = fmaxf(mx.x, v.x); mx.y = fmaxf(mx.y, v.y); mx.z = fmaxf(mx.z, v.z);
  }
  smin[threadIdx.x] = mn; smax[threadIdx.x] = mx;
  __syncthreads();
  for (int k = BLOCK / 2; k > 0; k >>= 1) {
    if (threadIdx.x < k) {
      float4 a = smin[threadIdx.x], c = smin[threadIdx.x + k];
      smin[threadIdx.x] = make_float4(fminf(a.x, c.x), fminf(a.y, c.y), fminf(a.z, c.z), 0);
      float4 d = smax[threadIdx.x], e = smax[threadIdx.x + k];
      smax[threadIdx.x] = make_float4(fmaxf(d.x, e.x), fmaxf(d.y, e.y), fmaxf(d.z, e.z), 0);
    }
    __syncthreads();
  }
  if (threadIdx.x == 0) { bbox[cb * 2] = smin[0]; bbox[cb * 2 + 1] = smax[0]; }
}

__device__ __forceinline__ unsigned spread3(unsigned v) {
  v = (v * 0x00010001u) & 0xFF0000FFu;
  v = (v * 0x00000101u) & 0x0F00F00Fu;
  v = (v * 0x00000011u) & 0xC30C30C3u;
  v = (v * 0x00000005u) & 0x49249249u;
  return v;
}

// Morton-sort one (cloud,batch) in LDS; 64 chunk-AABBs of 32 points each.
// Sort quality affects pruning speed only, never correctness.
__global__ __launch_bounds__(BLOCK) void sort_k(float4* __restrict__ pk1,
                                                float4* __restrict__ pk2,
                                                const float4* __restrict__ bbox,
                                                float4* __restrict__ chunkbox) {
  __shared__ float4 pts[Nn];                    // 32 KB
  __shared__ unsigned key[Nn];                  // 8 KB
  const int cb = blockIdx.x, tid = threadIdx.x;
  float4* p = (cb < 16 ? pk1 : pk2) + (cb & 15) * Nn;
  float4 lo = bbox[cb * 2], hi = bbox[cb * 2 + 1];
  float sx = 127.0f / fmaxf(hi.x - lo.x, 1e-9f);
  float sy = 127.0f / fmaxf(hi.y - lo.y, 1e-9f);
  float sz = 127.0f / fmaxf(hi.z - lo.z, 1e-9f);
  for (int i = tid; i < Nn; i += BLOCK) {
    float4 v = p[i];
    pts[i] = v;
    unsigned qx = (unsigned)fminf(fmaxf((v.x - lo.x) * sx, 0.f), 127.f);
    unsigned qy = (unsigned)fminf(fmaxf((v.y - lo.y) * sy, 0.f), 127.f);
    unsigned qz = (unsigned)fminf(fmaxf((v.z - lo.z) * sz, 0.f), 127.f);
    unsigned m = spread3(qx) | (spread3(qy) << 1) | (spread3(qz) << 2);
    key[i] = (m << 11) | (unsigned)i;
  }
  __syncthreads();
  for (int k = 2; k <= Nn; k <<= 1)
    for (int j = k >> 1; j > 0; j >>= 1) {
      for (int t = tid; t < Nn / 2; t += BLOCK) {
        int i = ((t & ~(j - 1)) << 1) | (t & (j - 1));
        int ixj = i | j;
        bool up = ((i & k) == 0);
        unsigned a = key[i], bq = key[ixj];
        if ((a > bq) == up) { key[i] = bq; key[ixj] = a; }
      }
      __syncthreads();
    }
  float4 g[Nn / BLOCK];
  #pragma unroll
  for (int c = 0; c < Nn / BLOCK; ++c)
    g[c] = pts[key[tid + c * BLOCK] & 2047u];
  __syncthreads();
  #pragma unroll
  for (int c = 0; c < Nn / BLOCK; ++c) {
    pts[tid + c * BLOCK] = g[c];
    p[tid + c * BLOCK]   = g[c];
  }
  __syncthreads();
  const int lane = tid & 63, wid = tid >> 6;
  for (int c2 = wid; c2 < 32; c2 += 4) {        // wave: chunk pair (2*c2, 2*c2+1)
    int c = 2 * c2 + (lane >> 5);
    float4 v = pts[c * 32 + (lane & 31)];
    float mnx = v.x, mny = v.y, mnz = v.z, mxx = v.x, mxy = v.y, mxz = v.z;
    #pragma unroll
    for (int off = 1; off < 32; off <<= 1) {    // stays within each 32-half
      mnx = fminf(mnx, __shfl_xor(mnx, off)); mny = fminf(mny, __shfl_xor(mny, off));
      mnz = fminf(mnz, __shfl_xor(mnz, off)); mxx = fmaxf(mxx, __shfl_xor(mxx, off));
      mxy = fmaxf(mxy, __shfl_xor(mxy, off)); mxz = fmaxf(mxz, __shfl_xor(mxz, off));
    }
    if ((lane & 31) == 0) {
      chunkbox[(cb * NCH + c) * 2]     = make_float4(mnx, mny, mnz, 0);
      chunkbox[(cb * NCH + c) * 2 + 1] = make_float4(mxx, mxy, mxz, 0);
    }
  }
}

// Fence-free hierarchical grid barrier (R15-proven): agent atomics only,
// release on arrival drains data stores to L3; no cache invalidation.
__device__ __forceinline__ void gbar(unsigned* bar, int b, int tid) {
  __syncthreads();
  if (tid == 0) {
    unsigned* cntG = bar;
    unsigned* genG = bar + 16;
    unsigned* arrB = bar + 32 + b * 16;
    unsigned* genB = bar + 288 + b * 16;
    unsigned g = __hip_atomic_load(genB, __ATOMIC_RELAXED, AGT);
    unsigned a = __hip_atomic_fetch_add(arrB, 1u, __ATOMIC_RELEASE, AGT);
    if (a == (unsigned)(BPB - 1)) {
      __hip_atomic_store(arrB, 0u, __ATOMIC_RELAXED, AGT);
      unsigned gg = __hip_atomic_load(genG, __ATOMIC_RELAXED, AGT);
      unsigned ag = __hip_atomic_fetch_add(cntG, 1u, __ATOMIC_ACQ_REL, AGT);
      if (ag == 15u) {
        __hip_atomic_store(cntG, 0u, __ATOMIC_RELAXED, AGT);
        __hip_atomic_store(genG, gg + 1u, __ATOMIC_RELEASE, AGT);
      } else {
        while (__hip_atomic_load(genG, __ATOMIC_RELAXED, AGT) == gg)
          __builtin_amdgcn_s_sleep(2);
      }
      __hip_atomic_store(genB, g + 1u, __ATOMIC_RELEASE, AGT);
    } else {
      while (__hip_atomic_load(genB, __ATOMIC_RELAXED, AGT) == g)
        __builtin_amdgcn_s_sleep(4);
    }
  }
  __syncthreads();
}

// One half-pass. NEW vs R15: column pots + chunk-max are staged ONCE per block
// into LDS via volatile loads (plain global_load with sc0/sc1: coherent at L3,
// coalesced, NO RMW-write traffic -- R15's 6.8 GB WRITE_SIZE killer), then the
// inner loop reads LDS. Also removes the 4x per-wave duplicate loads.
__device__ void half_pass(bool full,
    const float4* __restrict__ PRq, const float4* __restrict__ PC,
    const float* potC, float* potR,
    const float4* __restrict__ cboxC, const float* cmC,
    float* cmO, unsigned* slot,
    int sb, int lane, int wid, int tid, float thrAdd,
    float* red, float* redw, float* spot, float* scm) {
  const float log_ab = logf(1.0f / 2048.0f + 1e-8f);
  const float log2ab = log_ab * L2Ef;
  const float invC2  = 1.0f / C2f;
  const int base = sb * 32 + wid * 8;

  // ---- stage mutable column data (pre-scaled by C2f) ----
  {
    const volatile float* vp = (const volatile float*)potC;
    #pragma unroll
    for (int k = 0; k < Mm / BLOCK; ++k)
      spot[tid + k * BLOCK] = vp[tid + k * BLOCK] * C2f;
    if (tid < NCH) scm[tid] = ((const volatile float*)cmC)[tid] * C2f;
  }
  __syncthreads();

  float qx[8], qy[8], qz[8], K[8], up[8], S[8];
  #pragma unroll
  for (int r = 0; r < 8; ++r) {
    float4 q = PRq[base + r];                   // cached (immutable coords)
    qx[r] = q.x; qy[r] = q.y; qz[r] = q.z;
    up[r] = aload(&potR[base + r]);             // own rows, low count
    K[r]  = fmaf(up[r], -C2f, log2ab);
    S[r]  = 0.0f;
  }

  unsigned long long msk = ~0ull;
  if (!full) {
    float4 clo = cboxC[lane * 2], chi = cboxC[lane * 2 + 1];
    float cmw = scm[lane];
    unsigned long long m = 0;
    #pragma unroll
    for (int r = 0; r < 8; ++r) {
      float thr = (cmw - K[r] + thrAdd) * invC2;
      float ax = fmaxf(fmaxf(clo.x - qx[r], qx[r] - chi.x), 0.0f);
      float ay = fmaxf(fmaxf(clo.y - qy[r], qy[r] - chi.y), 0.0f);
      float az = fmaxf(fmaxf(clo.z - qz[r], qz[r] - chi.z), 0.0f);
      float d2low = fmaf(az, az, fmaf(ay, ay, ax * ax));
      bool keep = (thr > 0.0f) && (d2low <= thr * thr);
      m |= __ballot(keep);
    }
    msk = m;
  }

  while (msk) {                                 // two chunks per iteration
    int cA = __builtin_ctzll(msk); msk &= msk - 1;
    bool h2 = (msk != 0ull);
    int cB = cA;
    if (h2) { cB = __builtin_ctzll(msk); msk &= msk - 1; }
    int c = (lane < 32) ? cA : cB;
    int idx = c * 32 + (lane & 31);
    float4 f = PC[idx];                         // cached coords
    float w  = spot[idx];                       // LDS (pot*C2f)
    if (!h2 && lane >= 32) w = -3.0e38f;        // kill duplicate half
    #pragma unroll
    for (int r = 0; r < 8; ++r) {
      float dx = f.x - qx[r], dy = f.y - qy[r], dz = f.z - qz[r];
      float d2 = fmaf(dz, dz, fmaf(dy, dy, dx * dx));
      S[r] += ex2(fmaf(__builtin_amdgcn_sqrtf(d2), -C2f, w) - K[r]);
    }
  }

  float dmax = 0.0f, wmax = -3.0e38f;
  #pragma unroll
  for (int r = 0; r < 8; ++r) {
    float sv = S[r];
    #pragma unroll
    for (int off = 1; off < 64; off <<= 1) sv += __shfl_xor(sv, off);
    sv = fmaxf(sv, 1e-37f);
    float lse = (K[r] + __builtin_amdgcn_logf(sv)) * LN2f;  // v_log_f32 = log2
    float pnew = EPSf * (log_ab - lse);
    if (lane == 0) {
      dmax = fmaxf(dmax, fabsf(pnew - up[r]));
      astore(&potR[base + r], pnew);
      wmax = fmaxf(wmax, pnew);
    }
  }
  if (lane == 0) { red[wid] = dmax; redw[wid] = wmax; }
  __syncthreads();
  if (tid == 0) {
    float m = fmaxf(fmaxf(red[0], red[1]), fmaxf(red[2], red[3]));
    atomicMax(slot, __float_as_uint(m));
    float w = fmaxf(fmaxf(redw[0], redw[1]), fmaxf(redw[2], redw[3]));
    astore(&cmO[sb], w);                        // block = chunk: single writer
  }
  __syncthreads();
}

__global__ __launch_bounds__(BLOCK, 6) void sink_all(
    const float4* __restrict__ pk1, const float4* __restrict__ pk2,
    float* Upot, float* Vpot,
    unsigned* __restrict__ slots, const float4* __restrict__ cbox,
    float* cm, float* part,
    float* __restrict__ out, unsigned* __restrict__ bar) {
  __shared__ float spot[Mm];                    // 8 KB staged column pots
  __shared__ float scm[NCH];
  __shared__ float red[4], redw[4];
  __shared__ float convm;
  __shared__ double sd[BLOCK];
  const int bid = blockIdx.x, tid = threadIdx.x, lane = tid & 63, wid = tid >> 6;
  const int b = bid >> 6, sb = bid & 63;

  // prologue: zero potentials AND slots (poison-safe), then sync
  if (tid < 32) {
    astore(&Upot[b * Nn + sb * 32 + tid], 0.0f);
    astore(&Vpot[b * Nn + sb * 32 + tid], 0.0f);
  }
  for (int i = bid * BLOCK + tid; i < MAXIT * 16 * 16; i += PGRID * BLOCK)
    __hip_atomic_store(&slots[i], 0u, __ATOMIC_RELAXED, AGT);
  gbar(bar, b, tid);

  const float4* PK1 = pk1 + b * Nn;
  const float4* PK2 = pk2 + b * Nn;
  float* Ub = Upot + b * Nn;
  float* Vb = Vpot + b * Nn;
  const float4* cbox1 = cbox + b * NCH * 2;
  const float4* cbox2 = cbox + (16 + b) * NCH * 2;
  float* cm1 = cm + b * NCH;
  float* cm2 = cm + 1024 + b * NCH;

  for (int it = 0; it < MAXIT; ++it) {
    float thr = (it < 4) ? 120.0f : 80.0f;
    bool full = (it == 0);
    half_pass(full, PK1, PK2, Vb, Ub, cbox2, cm2, cm1,
              slots + (it * 16 + b) * 16 + 0, sb, lane, wid, tid, thr,
              red, redw, spot, scm);
    gbar(bar, b, tid);
    half_pass(full, PK2, PK1, Ub, Vb, cbox1, cm1, cm2,
              slots + (it * 16 + b) * 16 + 1, sb, lane, wid, tid, thr,
              red, redw, spot, scm);
    gbar(bar, b, tid);
    if (tid < 32) {
      float v = __uint_as_float(__hip_atomic_load(
          (const unsigned*)&slots[(it * 16 + (tid >> 1)) * 16 + (tid & 1)],
          __ATOMIC_RELAXED, AGT));
      #pragma unroll
      for (int off = 16; off >= 1; off >>= 1) v = fmaxf(v, __shfl_xor(v, off));
      if (tid == 0) convm = v;
    }
    __syncthreads();
    if (convm < TOLf) break;                    // uniform across all blocks
  }

  // final: sum exp((u+v-dist)/eps)*dist over this block's 32 rows
  {
    const volatile float* vv = (const volatile float*)Vb;
    #pragma unroll
    for (int k = 0; k < Mm / BLOCK; ++k)
      spot[tid + k * BLOCK] = vv[tid + k * BLOCK] * C2f;
    __syncthreads();
    const int base = sb * 32 + wid * 8;
    float qx[8], qy[8], qz[8], uc[8];
    #pragma unroll
    for (int r = 0; r < 8; ++r) {
      float4 q = PK1[base + r];
      qx[r] = q.x; qy[r] = q.y; qz[r] = q.z;
      uc[r] = aload(&Ub[base + r]) * C2f;
    }
    float acc = 0.0f;
    for (int t = 0; t < 32; ++t) {
      int idx = t * 64 + lane;
      float4 f = PK2[idx];
      float w  = spot[idx];
      #pragma unroll
      for (int r = 0; r < 8; ++r) {
        float dx = f.x - qx[r], dy = f.y - qy[r], dz = f.z - qz[r];
        float d2 = fmaf(dz, dz, fmaf(dy, dy, dx * dx));
        float td = __builtin_amdgcn_sqrtf(d2);
        acc = fmaf(ex2(fmaf(td, -C2f, w) + uc[r]), td, acc);
      }
    }
    #pragma unroll
    for (int off = 1; off < 64; off <<= 1) acc += __shfl_xor(acc, off);
    if (lane == 0) red[wid] = acc;
    __syncthreads();
    if (tid == 0)
      astore(&part[bid], (red[0] + red[1]) + (red[2] + red[3]));
  }
  gbar(bar, b, tid);

  if (bid == 0) {
    double s = 0.0;
    for (int i = tid; i < PGRID; i += BLOCK) s += (double)aload(&part[i]);
    sd[tid] = s;
    __syncthreads();
    for (int k = BLOCK / 2; k > 0; k >>= 1) {
      if (tid < k) sd[tid] += sd[tid + k];
      __syncthreads();
    }
    if (tid == 0) out[0] = (float)(sd[0] / (double)Bb);
  }
}

extern "C" void kernel_launch(void* const* d_in, const int* in_sizes, int n_in,
                              void* d_out, int out_size, void* d_ws, size_t ws_size,
                              hipStream_t stream) {
  (void)in_sizes; (void)n_in; (void)out_size; (void)ws_size;
  const float* p1 = (const float*)d_in[0];
  const float* p2 = (const float*)d_in[1];
  char* ws = (char*)d_ws;
  float4*   pk1   = (float4*)(ws + 0);          // 524288
  float4*   pk2   = (float4*)(ws + 524288);     // 524288
  float*    U     = (float*)(ws + 1048576);     // 131072
  float*    V     = (float*)(ws + 1179648);     // 131072
  unsigned* slots = (unsigned*)(ws + 1310720);  // 102400
  float*    part  = (float*)(ws + 1413120);     // 4096
  float4*   bbox  = (float4*)(ws + 1417216);    // 1024
  float4*   cbox  = (float4*)(ws + 1418240);    // 65536
  float*    cm    = (float*)(ws + 1483776);     // 8192
  unsigned* bar   = (unsigned*)(ws + 1491968);  // 4096

  const int npts = Bb * Nn;
  pack_pts<<<(npts + BLOCK - 1) / BLOCK, BLOCK, 0, stream>>>(p1, pk1, npts);
  pack_pts<<<(npts + BLOCK - 1) / BLOCK, BLOCK, 0, stream>>>(p2, pk2, npts);
  bbox_k<<<32, BLOCK, 0, stream>>>(pk1, pk2, bbox);
  sort_k<<<32, BLOCK, 0, stream>>>(pk1, pk2, bbox, cbox);
  init_bar<<<1, BLOCK, 0, stream>>>(bar);

  sink_all<<<PGRID, BLOCK, 0, stream>>>(pk1, pk2, U, V, slots, cbox, cm,
                                        part, (float*)d_out, bar);
}